// Round 4
// baseline (366.478 us; speedup 1.0000x reference)
//
#include <hip/hip_runtime.h>
#include <hip/hip_bf16.h>
#include <stdint.h>

typedef short short8 __attribute__((ext_vector_type(8)));
typedef short short4v __attribute__((ext_vector_type(4)));
typedef float f32x4 __attribute__((ext_vector_type(4)));

__device__ __forceinline__ unsigned short f2b(float x) {
  __hip_bfloat16 h = __float2bfloat16(x);
  return *reinterpret_cast<unsigned short*>(&h);
}

// global (AS1) -> LDS (AS3) direct 16B/lane copy. LDS dest is wave-uniform
// base + lane*16 implicit; global src is per-lane.
typedef __attribute__((address_space(1))) const void* gvp_t;
typedef __attribute__((address_space(3))) void* lvp_t;
__device__ __forceinline__ void gl2lds16(const void* g, void* l) {
  __builtin_amdgcn_global_load_lds((gvp_t)g, (lvp_t)l, 16, 0, 0);
}

// ---------------- X f32 -> bf16 (same layout) ----------------
__global__ void cvt_kernel(const float* __restrict__ in, unsigned short* __restrict__ out, int n4) {
  int i = blockIdx.x * blockDim.x + threadIdx.x;
  if (i >= n4) return;
  const float4 v = reinterpret_cast<const float4*>(in)[i];
  ushort4 o;
  o.x = f2b(v.x); o.y = f2b(v.y); o.z = f2b(v.z); o.w = f2b(v.w);
  reinterpret_cast<ushort4*>(out)[i] = o;
}

// ---------------- W[K][N] f32 -> Wt[N][K] bf16 ----------------
__global__ void tpose_kernel(const float* __restrict__ W, unsigned short* __restrict__ Wt,
                             int K, int N) {
  __shared__ float tile[32][33];
  const int nkb = K >> 5;
  const int bk = blockIdx.x % nkb, bn = blockIdx.x / nkb;
  const int k0 = bk * 32, n0 = bn * 32;
  const int tx = threadIdx.x & 31, ty = threadIdx.x >> 5;
#pragma unroll
  for (int i = 0; i < 4; i++) {
    int r = ty + i * 8;
    tile[r][tx] = W[(size_t)(k0 + r) * N + n0 + tx];
  }
  __syncthreads();
#pragma unroll
  for (int i = 0; i < 4; i++) {
    int r = ty + i * 8;
    Wt[(size_t)(n0 + r) * K + k0 + tx] = f2b(tile[tx][r]);
  }
}

// ---------------- V [bh][2048][64] -> Vt [bh][64][2048] ----------------
__global__ void vtpose_kernel(const unsigned short* __restrict__ Vb, unsigned short* __restrict__ Vt) {
  __shared__ unsigned short t[64][72];
  const int bh = blockIdx.x >> 5;
  const int s0 = (blockIdx.x & 31) * 64;
  const int tid = threadIdx.x;
  const int r = tid >> 3;        // 0..31
  const int c8 = (tid & 7) * 8;  // 0..56
  const unsigned short* src = Vb + ((size_t)bh * 2048 + s0) * 64;
#pragma unroll
  for (int i = 0; i < 2; i++) {
    short8 v = *reinterpret_cast<const short8*>(src + (size_t)(r + i * 32) * 64 + c8);
#pragma unroll
    for (int j = 0; j < 8; j++) t[r + i * 32][c8 + j] = (unsigned short)v[j];
  }
  __syncthreads();
  unsigned short* dst = Vt + (size_t)bh * 64 * 2048 + s0;
#pragma unroll
  for (int i = 0; i < 2; i++) {
    const int d = r + i * 32;
    short8 v;
#pragma unroll
    for (int j = 0; j < 8; j++) v[j] = (short)t[c8 + j][d];
    *reinterpret_cast<short8*>(dst + (size_t)d * 2048 + c8) = v;
  }
}

// ---------------- GEMM: C = A[M][K] * Bt[N][K]^T + bias, global_load_lds staging ----------------
template<int MODE>
__global__ __launch_bounds__(256)
void gemm_bt(const unsigned short* __restrict__ A, const unsigned short* __restrict__ Bt,
             const float* __restrict__ bias, void* __restrict__ out, int N) {
  constexpr int K = 1024;
  __shared__ __align__(16) unsigned short As[128 * 32];
  __shared__ __align__(16) unsigned short Bs[128 * 32];
  const int nbn = N >> 7;
  const int bm = blockIdx.x / nbn, bn = blockIdx.x % nbn;
  const int tid = threadIdx.x;
  const int lane = tid & 63, wave = tid >> 6;
  const int lo = lane & 15, g = lane >> 4;
  const int wr = (wave >> 1) * 64, wc = (wave & 1) * 64;

  const size_t arow0 = (size_t)bm * 128;
  const size_t brow0 = (size_t)bn * 128;

  f32x4 acc[4][4] = {};

  const int r_a = tid >> 2;
  const int c8 = (tid & 3) * 8;
  const unsigned short* gA0 = A + (arow0 + r_a) * K + c8;
  const unsigned short* gA1 = A + (arow0 + 64 + r_a) * K + c8;
  const unsigned short* gB0 = Bt + (brow0 + r_a) * K + c8;
  const unsigned short* gB1 = Bt + (brow0 + 64 + r_a) * K + c8;
  // LDS dest: wave-uniform base; lane*16B implicit -> As[tid*8..tid*8+7]
  unsigned short* lA0 = As + wave * 512;
  unsigned short* lA1 = As + 2048 + wave * 512;
  unsigned short* lB0 = Bs + wave * 512;
  unsigned short* lB1 = Bs + 2048 + wave * 512;

  for (int kb = 0; kb < K; kb += 32) {
    __syncthreads();  // previous tile fully consumed
    gl2lds16(gA0 + kb, lA0);
    gl2lds16(gA1 + kb, lA1);
    gl2lds16(gB0 + kb, lB0);
    gl2lds16(gB1 + kb, lB1);
    __syncthreads();  // vmcnt(0) drain before barrier -> tile ready
    short8 af[4], bf[4];
#pragma unroll
    for (int m = 0; m < 4; m++)
      af[m] = *reinterpret_cast<const short8*>(As + (wr + m * 16 + lo) * 32 + g * 8);
#pragma unroll
    for (int n = 0; n < 4; n++)
      bf[n] = *reinterpret_cast<const short8*>(Bs + (wc + n * 16 + lo) * 32 + g * 8);
#pragma unroll
    for (int m = 0; m < 4; m++)
#pragma unroll
      for (int n = 0; n < 4; n++)
        acc[m][n] = __builtin_amdgcn_mfma_f32_16x16x32_bf16(af[m], bf[n], acc[m][n], 0, 0, 0);
  }

#pragma unroll
  for (int m = 0; m < 4; m++) {
#pragma unroll
    for (int n = 0; n < 4; n++) {
      const int col = (int)brow0 + wc + n * 16 + lo;
      const float bv = bias[col];
#pragma unroll
      for (int r = 0; r < 4; r++) {
        const int row = (int)arow0 + wr + m * 16 + g * 4 + r;
        const float v = acc[m][n][r] + bv;
        if (MODE == 0) {
          unsigned short* dst = reinterpret_cast<unsigned short*>(out);
          const int which = col >> 10, rem = col & 1023;
          const int h = rem >> 6, d = rem & 63;
          const int b = row >> 11, s = row & 2047;
          const size_t idx = ((size_t)which * 32 + (size_t)(b * 16 + h)) * 2048 * 64 +
                             (size_t)s * 64 + d;
          dst[idx] = f2b(v);
        } else {
          reinterpret_cast<float*>(out)[(size_t)row * N + col] = v;
        }
      }
    }
  }
}

// ---------------- causal flash attention ----------------
// Q/K: [bh][2048][64] bf16. Vt: [bh][64][2048] bf16. Out Ab: [B][S][H*64] bf16.
// LPT order: longest q-blocks launch first. Prefetched K/V fragments.
__device__ __forceinline__ short8 ldv8(const unsigned short* p) {
  short4v x = *reinterpret_cast<const short4v*>(p);
  short4v y = *reinterpret_cast<const short4v*>(p + 16);
  return __builtin_shufflevector(x, y, 0, 1, 2, 3, 4, 5, 6, 7);
}

__global__ __launch_bounds__(256)
void attn_kernel(const unsigned short* __restrict__ Qb, const unsigned short* __restrict__ Kb,
                 const unsigned short* __restrict__ Vt, unsigned short* __restrict__ Ab) {
  constexpr int S = 2048, HD = 64;
  const int tid = threadIdx.x;
  const int lane = tid & 63, wave = tid >> 6;
  const int lo = lane & 15, g = lane >> 4;
  const int qblk = 31 - (blockIdx.x >> 5);  // LPT: big tiles first
  const int bh = blockIdx.x & 31;
  const int qbase = qblk * 64 + wave * 16;
  const unsigned short* Qh = Qb + (size_t)bh * S * HD;
  const unsigned short* Kh = Kb + (size_t)bh * S * HD;
  const unsigned short* Vh = Vt + (size_t)bh * HD * S;

  const short8 qf0 = *reinterpret_cast<const short8*>(Qh + (size_t)(qbase + lo) * HD + g * 8);
  const short8 qf1 = *reinterpret_cast<const short8*>(Qh + (size_t)(qbase + lo) * HD + 32 + g * 8);

  float mrun = -1e30f, lsum = 0.f;
  f32x4 o0 = {}, o1 = {}, o2 = {}, o3 = {};
  const int q_lane = qbase + lo;
  const int nchunk = (qbase + 47) >> 5;

  // K frag base: row lo, dims g*8; chunk c at +c*2048, subtile t at +1024, half at +32
  const unsigned short* kb0 = Kh + (size_t)lo * HD + g * 8;
  // V frag base: row d=lo (+16X -> +32768X), col g*4; chunk c at +c*32, k+16 at +16
  const unsigned short* vb0 = Vh + (size_t)lo * S + g * 4;

#define LDK(c, a, b, cc, d)                                          \
  { const unsigned short* p = kb0 + (size_t)(c) * 2048;              \
    a  = *reinterpret_cast<const short8*>(p);                        \
    b  = *reinterpret_cast<const short8*>(p + 32);                   \
    cc = *reinterpret_cast<const short8*>(p + 1024);                 \
    d  = *reinterpret_cast<const short8*>(p + 1024 + 32); }
#define LDV(c, a, b, cc, d)                                          \
  { const unsigned short* p = vb0 + (size_t)(c) * 32;                \
    a  = ldv8(p);                                                    \
    b  = ldv8(p + 32768);                                            \
    cc = ldv8(p + 65536);                                            \
    d  = ldv8(p + 98304); }

  short8 kf00, kf01, kf10, kf11, vf0, vf1, vf2, vf3;
  LDK(0, kf00, kf01, kf10, kf11);
  LDV(0, vf0, vf1, vf2, vf3);

  for (int c = 0; c < nchunk; ++c) {
    const int cn = (c + 1 < nchunk) ? c + 1 : c;
    short8 nk00, nk01, nk10, nk11, nv0, nv1, nv2, nv3;
    LDK(cn, nk00, nk01, nk10, nk11);
    LDV(cn, nv0, nv1, nv2, nv3);

    const int kk0 = c * 32;
    f32x4 z0 = {0.f, 0.f, 0.f, 0.f}, z1 = {0.f, 0.f, 0.f, 0.f};
    z0 = __builtin_amdgcn_mfma_f32_16x16x32_bf16(kf00, qf0, z0, 0, 0, 0);
    z0 = __builtin_amdgcn_mfma_f32_16x16x32_bf16(kf01, qf1, z0, 0, 0, 0);
    z1 = __builtin_amdgcn_mfma_f32_16x16x32_bf16(kf10, qf0, z1, 0, 0, 0);
    z1 = __builtin_amdgcn_mfma_f32_16x16x32_bf16(kf11, qf1, z1, 0, 0, 0);

    float s[8];
#pragma unroll
    for (int j = 0; j < 8; j++) {
      const int kk = kk0 + ((j >> 2) << 4) + g * 4 + (j & 3);
      const float v = ((j >> 2) ? z1[j & 3] : z0[j & 3]) * 0.125f;
      s[j] = (kk > q_lane) ? -10000.f : v;
    }
    float tmax = s[0];
#pragma unroll
    for (int j = 1; j < 8; j++) tmax = fmaxf(tmax, s[j]);
    tmax = fmaxf(tmax, __shfl_xor(tmax, 16));
    tmax = fmaxf(tmax, __shfl_xor(tmax, 32));
    const float mn = fmaxf(mrun, tmax);
    const float cf = __expf(mrun - mn);
    mrun = mn;
    float ps = 0.f;
    short8 pf;
#pragma unroll
    for (int j = 0; j < 8; j++) {
      const float p = __expf(s[j] - mn);
      ps += p;
      pf[j] = (short)f2b(p);
    }
    lsum = lsum * cf + ps;
#pragma unroll
    for (int r = 0; r < 4; r++) {
      const float cr = __shfl(cf, g * 4 + r);
      o0[r] *= cr; o1[r] *= cr; o2[r] *= cr; o3[r] *= cr;
    }
    o0 = __builtin_amdgcn_mfma_f32_16x16x32_bf16(pf, vf0, o0, 0, 0, 0);
    o1 = __builtin_amdgcn_mfma_f32_16x16x32_bf16(pf, vf1, o1, 0, 0, 0);
    o2 = __builtin_amdgcn_mfma_f32_16x16x32_bf16(pf, vf2, o2, 0, 0, 0);
    o3 = __builtin_amdgcn_mfma_f32_16x16x32_bf16(pf, vf3, o3, 0, 0, 0);

    kf00 = nk00; kf01 = nk01; kf10 = nk10; kf11 = nk11;
    vf0 = nv0; vf1 = nv1; vf2 = nv2; vf3 = nv3;
  }
#undef LDK
#undef LDV

  lsum += __shfl_xor(lsum, 16);
  lsum += __shfl_xor(lsum, 32);

  const int b = bh >> 4, h = bh & 15;
#pragma unroll
  for (int r = 0; r < 4; r++) {
    const float li = 1.f / __shfl(lsum, g * 4 + r);
    const int srow = qbase + g * 4 + r;
    unsigned short* dst = Ab + ((size_t)b * S + srow) * 1024 + h * 64 + lo;
    dst[0]  = f2b(o0[r] * li);
    dst[16] = f2b(o1[r] * li);
    dst[32] = f2b(o2[r] * li);
    dst[48] = f2b(o3[r] * li);
  }
}

extern "C" void kernel_launch(void* const* d_in, const int* in_sizes, int n_in,
                              void* d_out, int out_size, void* d_ws, size_t ws_size,
                              hipStream_t stream) {
  const float* hs       = (const float*)d_in[0];
  const float* c_attn_w = (const float*)d_in[1];
  const float* c_attn_b = (const float*)d_in[2];
  const float* c_proj_w = (const float*)d_in[3];
  const float* c_proj_b = (const float*)d_in[4];

  char* ws = (char*)d_ws;
  unsigned short* Xb    = (unsigned short*)ws;  ws += (size_t)4096 * 1024 * 2;   // 8 MB
  unsigned short* Wqkvt = (unsigned short*)ws;  ws += (size_t)3072 * 1024 * 2;   // 6 MB
  unsigned short* Wpt   = (unsigned short*)ws;  ws += (size_t)1024 * 1024 * 2;   // 2 MB
  unsigned short* QKV   = (unsigned short*)ws;  ws += (size_t)3 * 32 * 2048 * 64 * 2;  // 24 MB
  unsigned short* Ab    = (unsigned short*)ws;  ws += (size_t)4096 * 1024 * 2;   // 8 MB

  unsigned short* Qb = QKV;
  unsigned short* Kb = QKV + (size_t)32 * 2048 * 64;
  unsigned short* Vb = QKV + (size_t)2 * 32 * 2048 * 64;
  // Vt aliases Xb: Xb's last read is gemm_bt<0>; vtpose runs after it (stream-ordered).
  unsigned short* Vt = Xb;

  cvt_kernel<<<4096, 256, 0, stream>>>(hs, Xb, 4096 * 1024 / 4);
  tpose_kernel<<<(1024 / 32) * (3072 / 32), 256, 0, stream>>>(c_attn_w, Wqkvt, 1024, 3072);
  tpose_kernel<<<(1024 / 32) * (1024 / 32), 256, 0, stream>>>(c_proj_w, Wpt, 1024, 1024);
  gemm_bt<0><<<32 * 24, 256, 0, stream>>>(Xb, Wqkvt, c_attn_b, QKV, 3072);
  vtpose_kernel<<<32 * 32, 256, 0, stream>>>(Vb, Vt);
  attn_kernel<<<32 * 32, 256, 0, stream>>>(Qb, Kb, Vt, Ab);
  gemm_bt<1><<<32 * 8, 256, 0, stream>>>(Ab, Wpt, c_proj_b, d_out, 1024);
}

// Round 10
// 212.138 us; speedup vs baseline: 1.7275x; 1.7275x over previous
//
#include <hip/hip_runtime.h>
#include <hip/hip_bf16.h>
#include <stdint.h>

typedef short short8 __attribute__((ext_vector_type(8)));
typedef short short4v __attribute__((ext_vector_type(4)));
typedef float f32x4 __attribute__((ext_vector_type(4)));

__device__ __forceinline__ unsigned short f2b(float x) {
  __hip_bfloat16 h = __float2bfloat16(x);
  return *reinterpret_cast<unsigned short*>(&h);
}

typedef __attribute__((address_space(1))) const void* gvp_t;
typedef __attribute__((address_space(3))) void* lvp_t;
__device__ __forceinline__ void gl2lds16(const void* g, void* l) {
  __builtin_amdgcn_global_load_lds((gvp_t)g, (lvp_t)l, 16, 0, 0);
}

// ---------------- X f32 -> bf16 ----------------
__global__ void cvt_kernel(const float* __restrict__ in, unsigned short* __restrict__ out, int n4) {
  int i = blockIdx.x * blockDim.x + threadIdx.x;
  if (i >= n4) return;
  const float4 v = reinterpret_cast<const float4*>(in)[i];
  ushort4 o;
  o.x = f2b(v.x); o.y = f2b(v.y); o.z = f2b(v.z); o.w = f2b(v.w);
  reinterpret_cast<ushort4*>(out)[i] = o;
}

// ---------------- W[K][N] f32 -> Wt[N][K] bf16 ----------------
__global__ void tpose_kernel(const float* __restrict__ W, unsigned short* __restrict__ Wt,
                             int K, int N) {
  __shared__ float tile[32][33];
  const int nkb = K >> 5;
  const int bk = blockIdx.x % nkb, bn = blockIdx.x / nkb;
  const int k0 = bk * 32, n0 = bn * 32;
  const int tx = threadIdx.x & 31, ty = threadIdx.x >> 5;
#pragma unroll
  for (int i = 0; i < 4; i++) {
    int r = ty + i * 8;
    tile[r][tx] = W[(size_t)(k0 + r) * N + n0 + tx];
  }
  __syncthreads();
#pragma unroll
  for (int i = 0; i < 4; i++) {
    int r = ty + i * 8;
    Wt[(size_t)(n0 + r) * K + k0 + tx] = f2b(tile[tx][r]);
  }
}

// ---------------- V [bh][2048][64] -> Vt [bh][64][2048] ----------------
__global__ void vtpose_kernel(const unsigned short* __restrict__ Vb, unsigned short* __restrict__ Vt) {
  __shared__ unsigned short t[64][72];
  const int bh = blockIdx.x >> 5;
  const int s0 = (blockIdx.x & 31) * 64;
  const int tid = threadIdx.x;
  const int r = tid >> 3;
  const int c8 = (tid & 7) * 8;
  const unsigned short* src = Vb + ((size_t)bh * 2048 + s0) * 64;
#pragma unroll
  for (int i = 0; i < 2; i++) {
    short8 v = *reinterpret_cast<const short8*>(src + (size_t)(r + i * 32) * 64 + c8);
#pragma unroll
    for (int j = 0; j < 8; j++) t[r + i * 32][c8 + j] = (unsigned short)v[j];
  }
  __syncthreads();
  unsigned short* dst = Vt + (size_t)bh * 64 * 2048 + s0;
#pragma unroll
  for (int i = 0; i < 2; i++) {
    const int d = r + i * 32;
    short8 v;
#pragma unroll
    for (int j = 0; j < 8; j++) v[j] = (short)t[c8 + j][d];
    *reinterpret_cast<short8*>(dst + (size_t)d * 2048 + c8) = v;
  }
}

// ---------------- GEMM: C = A[M][K] * Bt[N][K]^T + bias ----------------
template<int MODE>
__global__ __launch_bounds__(256)
void gemm_bt(const unsigned short* __restrict__ A, const unsigned short* __restrict__ Bt,
             const float* __restrict__ bias, void* __restrict__ out, int N) {
  constexpr int K = 1024;
  __shared__ __align__(16) unsigned short As[128 * 32];
  __shared__ __align__(16) unsigned short Bs[128 * 32];
  const int nbn = N >> 7;
  const int bm = blockIdx.x / nbn, bn = blockIdx.x % nbn;
  const int tid = threadIdx.x;
  const int lane = tid & 63, wave = tid >> 6;
  const int lo = lane & 15, g = lane >> 4;
  const int wr = (wave >> 1) * 64, wc = (wave & 1) * 64;

  const size_t arow0 = (size_t)bm * 128;
  const size_t brow0 = (size_t)bn * 128;

  f32x4 acc[4][4] = {};

  const int r_a = tid >> 2;
  const int c8 = (tid & 3) * 8;
  const unsigned short* gA0 = A + (arow0 + r_a) * K + c8;
  const unsigned short* gA1 = A + (arow0 + 64 + r_a) * K + c8;
  const unsigned short* gB0 = Bt + (brow0 + r_a) * K + c8;
  const unsigned short* gB1 = Bt + (brow0 + 64 + r_a) * K + c8;
  unsigned short* lA0 = As + wave * 512;
  unsigned short* lA1 = As + 2048 + wave * 512;
  unsigned short* lB0 = Bs + wave * 512;
  unsigned short* lB1 = Bs + 2048 + wave * 512;

  for (int kb = 0; kb < K; kb += 32) {
    __syncthreads();
    gl2lds16(gA0 + kb, lA0);
    gl2lds16(gA1 + kb, lA1);
    gl2lds16(gB0 + kb, lB0);
    gl2lds16(gB1 + kb, lB1);
    __syncthreads();
    short8 af[4], bf[4];
#pragma unroll
    for (int m = 0; m < 4; m++)
      af[m] = *reinterpret_cast<const short8*>(As + (wr + m * 16 + lo) * 32 + g * 8);
#pragma unroll
    for (int n = 0; n < 4; n++)
      bf[n] = *reinterpret_cast<const short8*>(Bs + (wc + n * 16 + lo) * 32 + g * 8);
#pragma unroll
    for (int m = 0; m < 4; m++)
#pragma unroll
      for (int n = 0; n < 4; n++)
        acc[m][n] = __builtin_amdgcn_mfma_f32_16x16x32_bf16(af[m], bf[n], acc[m][n], 0, 0, 0);
  }

#pragma unroll
  for (int m = 0; m < 4; m++) {
#pragma unroll
    for (int n = 0; n < 4; n++) {
      const int col = (int)brow0 + wc + n * 16 + lo;
      const float bv = bias[col];
#pragma unroll
      for (int r = 0; r < 4; r++) {
        const int row = (int)arow0 + wr + m * 16 + g * 4 + r;
        const float v = acc[m][n][r] + bv;
        if (MODE == 0) {
          unsigned short* dst = reinterpret_cast<unsigned short*>(out);
          const int which = col >> 10, rem = col & 1023;
          const int h = rem >> 6, d = rem & 63;
          const int b = row >> 11, s = row & 2047;
          const size_t idx = ((size_t)which * 32 + (size_t)(b * 16 + h)) * 2048 * 64 +
                             (size_t)s * 64 + d;
          dst[idx] = f2b(v);
        } else {
          reinterpret_cast<float*>(out)[(size_t)row * N + col] = v;
        }
      }
    }
  }
}

// ---------------- causal flash attention, block-cooperative LDS staging ----------------
// Q/K: [bh][2048][64]. Vt: [bh][64][2048]. Out Ab: [B][S][H*64].
// Block = 4 waves = 64 q-rows; K/V tiles (KVBLK=64, 2 sub-chunks of 32) staged in LDS,
// double-buffered, swizzled both-sides (pre-swizzled global src + swizzled ds_read).
__global__ __launch_bounds__(256, 4)
void attn_kernel(const unsigned short* __restrict__ Qb, const unsigned short* __restrict__ Kb,
                 const unsigned short* __restrict__ Vt, unsigned short* __restrict__ Ab) {
  constexpr int S = 2048, HD = 64;
  __shared__ __align__(16) unsigned short Ks[2][2][2048];  // [buf][sub][32 k][64 d], row 128B, swz unit^= (row&7)
  __shared__ __align__(16) unsigned short Vs[2][2][2048];  // [buf][sub][64 d][32 k], row 64B, 16B-unit swz ^= (d&3)
  const int tid = threadIdx.x;
  const int lane = tid & 63, wave = tid >> 6;
  const int lo = lane & 15, g = lane >> 4;
  const int qblk = 31 - (blockIdx.x >> 5);  // LPT: big tiles first
  const int bh = blockIdx.x & 31;           // bh-interleave: 4 heads per XCD
  const int qbase = qblk * 64 + wave * 16;
  const unsigned short* Qh = Qb + (size_t)bh * S * HD;
  const unsigned short* Kh = Kb + (size_t)bh * S * HD;
  const unsigned short* Vh = Vt + (size_t)bh * HD * S;

  const short8 qf0 = *reinterpret_cast<const short8*>(Qh + (size_t)(qbase + lo) * HD + g * 8);
  const short8 qf1 = *reinterpret_cast<const short8*>(Qh + (size_t)(qbase + lo) * HD + 32 + g * 8);

  // --- staging source addresses (pre-swizzled global; LDS write is linear tid*16B) ---
  const int kr = tid >> 3, ku = tid & 7;               // K sub-tile: row 0..31, 16B unit 0..7
  const unsigned short* kgs = Kh + (size_t)kr * HD + ((ku ^ (kr & 7)) << 3);
  const int vd = tid >> 2, vu = tid & 3;               // V sub-tile: row d 0..63, 16B unit 0..3
  const unsigned short* vgs = Vh + (size_t)vd * S + ((vu ^ (vd & 3)) << 3);
  const int woff = wave * 512;  // elements; gl2lds adds lane*16B

#define STAGE(tt, bb)                                                    \
  { const int k0e = (tt) * 64;                                           \
    gl2lds16(kgs + (size_t)k0e * HD,        &Ks[bb][0][woff]);           \
    gl2lds16(kgs + (size_t)(k0e + 32) * HD, &Ks[bb][1][woff]);           \
    gl2lds16(vgs + k0e,                     &Vs[bb][0][woff]);           \
    gl2lds16(vgs + k0e + 32,                &Vs[bb][1][woff]); }

  // --- swizzled read offsets (elements) ---
  const int kswz0 = ((g ^ (lo & 7)) << 3);         // d-unit g
  const int kswz1 = (((g + 4) ^ (lo & 7)) << 3);   // d-unit g+4 (d+32)
  const int vsw0 = ((((g >> 1)) ^ (lo & 3)) << 3) + (g & 1) * 4;      // k = 4g..4g+3
  const int vsw1 = ((((g >> 1) + 2) ^ (lo & 3)) << 3) + (g & 1) * 4;  // k+16

  float mrun = -1e30f, lsum = 0.f;
  f32x4 o0 = {}, o1 = {}, o2 = {}, o3 = {};
  const int q_lane = qbase + lo;
  const int nt = qblk + 1;

  STAGE(0, 0);
  __syncthreads();

  int buf = 0;
  for (int t = 0; t < nt; ++t) {
    if (t + 1 < nt) STAGE(t + 1, buf ^ 1);  // issue-early: latency hides under compute
#pragma unroll
    for (int sc = 0; sc < 2; ++sc) {
      const unsigned short* Kt = &Ks[buf][sc][0];
      const unsigned short* Vl = &Vs[buf][sc][0];
      const int kk0 = t * 64 + sc * 32;

      const short8 kf00 = *reinterpret_cast<const short8*>(Kt + lo * 64 + kswz0);
      const short8 kf01 = *reinterpret_cast<const short8*>(Kt + lo * 64 + kswz1);
      const short8 kf10 = *reinterpret_cast<const short8*>(Kt + (16 + lo) * 64 + kswz0);
      const short8 kf11 = *reinterpret_cast<const short8*>(Kt + (16 + lo) * 64 + kswz1);

      f32x4 z0 = {0.f, 0.f, 0.f, 0.f}, z1 = {0.f, 0.f, 0.f, 0.f};
      __builtin_amdgcn_s_setprio(1);
      z0 = __builtin_amdgcn_mfma_f32_16x16x32_bf16(kf00, qf0, z0, 0, 0, 0);
      z0 = __builtin_amdgcn_mfma_f32_16x16x32_bf16(kf01, qf1, z0, 0, 0, 0);
      z1 = __builtin_amdgcn_mfma_f32_16x16x32_bf16(kf10, qf0, z1, 0, 0, 0);
      z1 = __builtin_amdgcn_mfma_f32_16x16x32_bf16(kf11, qf1, z1, 0, 0, 0);
      __builtin_amdgcn_s_setprio(0);

      float s[8];
#pragma unroll
      for (int j = 0; j < 8; j++) {
        const int kk = kk0 + ((j >> 2) << 4) + g * 4 + (j & 3);
        const float v = ((j >> 2) ? z1[j & 3] : z0[j & 3]) * 0.125f;
        s[j] = (kk > q_lane) ? -10000.f : v;
      }
      float tmax = s[0];
#pragma unroll
      for (int j = 1; j < 8; j++) tmax = fmaxf(tmax, s[j]);
      tmax = fmaxf(tmax, __shfl_xor(tmax, 16));
      tmax = fmaxf(tmax, __shfl_xor(tmax, 32));
      const float mn = fmaxf(mrun, tmax);
      const float cf = __expf(mrun - mn);
      mrun = mn;
      float ps = 0.f;
      short8 pf;
#pragma unroll
      for (int j = 0; j < 8; j++) {
        const float p = __expf(s[j] - mn);
        ps += p;
        pf[j] = (short)f2b(p);
      }
      lsum = lsum * cf + ps;
#pragma unroll
      for (int r = 0; r < 4; r++) {
        const float cr = __shfl(cf, g * 4 + r);
        o0[r] *= cr; o1[r] *= cr; o2[r] *= cr; o3[r] *= cr;
      }

      short8 vf0, vf1, vf2, vf3;
      {
        short4v a0 = *reinterpret_cast<const short4v*>(Vl + (lo +  0) * 32 + vsw0);
        short4v b0 = *reinterpret_cast<const short4v*>(Vl + (lo +  0) * 32 + vsw1);
        short4v a1 = *reinterpret_cast<const short4v*>(Vl + (lo + 16) * 32 + vsw0);
        short4v b1 = *reinterpret_cast<const short4v*>(Vl + (lo + 16) * 32 + vsw1);
        short4v a2 = *reinterpret_cast<const short4v*>(Vl + (lo + 32) * 32 + vsw0);
        short4v b2 = *reinterpret_cast<const short4v*>(Vl + (lo + 32) * 32 + vsw1);
        short4v a3 = *reinterpret_cast<const short4v*>(Vl + (lo + 48) * 32 + vsw0);
        short4v b3 = *reinterpret_cast<const short4v*>(Vl + (lo + 48) * 32 + vsw1);
        vf0 = __builtin_shufflevector(a0, b0, 0, 1, 2, 3, 4, 5, 6, 7);
        vf1 = __builtin_shufflevector(a1, b1, 0, 1, 2, 3, 4, 5, 6, 7);
        vf2 = __builtin_shufflevector(a2, b2, 0, 1, 2, 3, 4, 5, 6, 7);
        vf3 = __builtin_shufflevector(a3, b3, 0, 1, 2, 3, 4, 5, 6, 7);
      }
      __builtin_amdgcn_s_setprio(1);
      o0 = __builtin_amdgcn_mfma_f32_16x16x32_bf16(pf, vf0, o0, 0, 0, 0);
      o1 = __builtin_amdgcn_mfma_f32_16x16x32_bf16(pf, vf1, o1, 0, 0, 0);
      o2 = __builtin_amdgcn_mfma_f32_16x16x32_bf16(pf, vf2, o2, 0, 0, 0);
      o3 = __builtin_amdgcn_mfma_f32_16x16x32_bf16(pf, vf3, o3, 0, 0, 0);
      __builtin_amdgcn_s_setprio(0);
    }
    __syncthreads();  // drains stage loads (vmcnt 0) + orders buffer reuse
    buf ^= 1;
  }
#undef STAGE

  lsum += __shfl_xor(lsum, 16);
  lsum += __shfl_xor(lsum, 32);

  const int b = bh >> 4, h = bh & 15;
#pragma unroll
  for (int r = 0; r < 4; r++) {
    const float li = 1.f / __shfl(lsum, g * 4 + r);
    const int srow = qbase + g * 4 + r;
    unsigned short* dst = Ab + ((size_t)b * S + srow) * 1024 + h * 64 + lo;
    dst[0]  = f2b(o0[r] * li);
    dst[16] = f2b(o1[r] * li);
    dst[32] = f2b(o2[r] * li);
    dst[48] = f2b(o3[r] * li);
  }
}

extern "C" void kernel_launch(void* const* d_in, const int* in_sizes, int n_in,
                              void* d_out, int out_size, void* d_ws, size_t ws_size,
                              hipStream_t stream) {
  const float* hs       = (const float*)d_in[0];
  const float* c_attn_w = (const float*)d_in[1];
  const float* c_attn_b = (const float*)d_in[2];
  const float* c_proj_w = (const float*)d_in[3];
  const float* c_proj_b = (const float*)d_in[4];

  char* ws = (char*)d_ws;
  unsigned short* Xb    = (unsigned short*)ws;  ws += (size_t)4096 * 1024 * 2;
  unsigned short* Wqkvt = (unsigned short*)ws;  ws += (size_t)3072 * 1024 * 2;
  unsigned short* Wpt   = (unsigned short*)ws;  ws += (size_t)1024 * 1024 * 2;
  unsigned short* QKV   = (unsigned short*)ws;  ws += (size_t)3 * 32 * 2048 * 64 * 2;
  unsigned short* Ab    = (unsigned short*)ws;  ws += (size_t)4096 * 1024 * 2;

  unsigned short* Qb = QKV;
  unsigned short* Kb = QKV + (size_t)32 * 2048 * 64;
  unsigned short* Vb = QKV + (size_t)2 * 32 * 2048 * 64;
  unsigned short* Vt = Xb;  // aliases Xb (dead after gemm_bt<0>)

  cvt_kernel<<<4096, 256, 0, stream>>>(hs, Xb, 4096 * 1024 / 4);
  tpose_kernel<<<(1024 / 32) * (3072 / 32), 256, 0, stream>>>(c_attn_w, Wqkvt, 1024, 3072);
  tpose_kernel<<<(1024 / 32) * (1024 / 32), 256, 0, stream>>>(c_proj_w, Wpt, 1024, 1024);
  gemm_bt<0><<<32 * 24, 256, 0, stream>>>(Xb, Wqkvt, c_attn_b, QKV, 3072);
  vtpose_kernel<<<32 * 32, 256, 0, stream>>>(Vb, Vt);
  attn_kernel<<<32 * 32, 256, 0, stream>>>(Qb, Kb, Vt, Ab);
  gemm_bt<1><<<32 * 8, 256, 0, stream>>>(Ab, Wpt, c_proj_b, d_out, 1024);
}

// Round 13
// 209.528 us; speedup vs baseline: 1.7491x; 1.0125x over previous
//
#include <hip/hip_runtime.h>
#include <hip/hip_bf16.h>
#include <stdint.h>

typedef short short8 __attribute__((ext_vector_type(8)));
typedef short short4v __attribute__((ext_vector_type(4)));
typedef float f32x4 __attribute__((ext_vector_type(4)));

__device__ __forceinline__ unsigned short f2b(float x) {
  __hip_bfloat16 h = __float2bfloat16(x);
  return *reinterpret_cast<unsigned short*>(&h);
}

typedef __attribute__((address_space(1))) const void* gvp_t;
typedef __attribute__((address_space(3))) void* lvp_t;
__device__ __forceinline__ void gl2lds16(const void* g, void* l) {
  __builtin_amdgcn_global_load_lds((gvp_t)g, (lvp_t)l, 16, 0, 0);
}

// ---------------- prep: X cvt (blocks 0..4095) + W_qkv tpose (4096..7167) + W_proj tpose (7168..8191) ----------------
__global__ void prep_kernel(const float* __restrict__ hs, unsigned short* __restrict__ Xb,
                            const float* __restrict__ Wqkv, unsigned short* __restrict__ Wqkvt,
                            const float* __restrict__ Wp, unsigned short* __restrict__ Wpt) {
  __shared__ float tile[32][33];
  const int bid = blockIdx.x;
  if (bid < 4096) {
    const int i = bid * 256 + threadIdx.x;
    const float4 v = reinterpret_cast<const float4*>(hs)[i];
    ushort4 o;
    o.x = f2b(v.x); o.y = f2b(v.y); o.z = f2b(v.z); o.w = f2b(v.w);
    reinterpret_cast<ushort4*>(Xb)[i] = o;
    return;
  }
  const float* W;
  unsigned short* Wt;
  int idx, N;
  if (bid < 4096 + 3072) { idx = bid - 4096; W = Wqkv; Wt = Wqkvt; N = 3072; }
  else                   { idx = bid - 7168; W = Wp;   Wt = Wpt;   N = 1024; }
  const int nkb = 32;  // K=1024
  const int bk = idx % nkb, bn = idx / nkb;
  const int k0 = bk * 32, n0 = bn * 32;
  const int tx = threadIdx.x & 31, ty = threadIdx.x >> 5;
#pragma unroll
  for (int i = 0; i < 4; i++) {
    int r = ty + i * 8;
    tile[r][tx] = W[(size_t)(k0 + r) * N + n0 + tx];
  }
  __syncthreads();
#pragma unroll
  for (int i = 0; i < 4; i++) {
    int r = ty + i * 8;
    Wt[(size_t)(n0 + r) * 1024 + k0 + tx] = f2b(tile[tx][r]);
  }
}

// ---------------- GEMM: C = A[M][K] * Bt[N][K]^T + bias, dbuf 2-phase pipeline ----------------
// MODE 0: QKV epilogue -> Q/K bf16 [bh][s][64]; V written TRANSPOSED [bh][d][s].
// MODE 1: proj epilogue -> f32 out [M][N].
template<int MODE>
__global__ __launch_bounds__(256)
void gemm_bt(const unsigned short* __restrict__ A, const unsigned short* __restrict__ Bt,
             const float* __restrict__ bias, void* __restrict__ out, int N) {
  constexpr int K = 1024;
  constexpr int NT = K / 32;
  __shared__ __align__(16) unsigned short As[2][128 * 32];
  __shared__ __align__(16) unsigned short Bs[2][128 * 32];
  const int nbn = N >> 7;
  const int bm = blockIdx.x / nbn, bn = blockIdx.x % nbn;
  const int tid = threadIdx.x;
  const int lane = tid & 63, wave = tid >> 6;
  const int lo = lane & 15, g = lane >> 4;
  const int wr = (wave >> 1) * 64, wc = (wave & 1) * 64;

  const size_t arow0 = (size_t)bm * 128;
  const size_t brow0 = (size_t)bn * 128;

  f32x4 acc[4][4] = {};

  const int r_a = tid >> 2;
  const int c8 = (tid & 3) * 8;
  const unsigned short* gA0 = A + (arow0 + r_a) * K + c8;
  const unsigned short* gA1 = A + (arow0 + 64 + r_a) * K + c8;
  const unsigned short* gB0 = Bt + (brow0 + r_a) * K + c8;
  const unsigned short* gB1 = Bt + (brow0 + 64 + r_a) * K + c8;
  const int woff = wave * 512;  // gl2lds adds lane*16B

#define GSTAGE(tt, bb)                                        \
  { const int kb = (tt) * 32;                                 \
    gl2lds16(gA0 + kb, &As[bb][woff]);                        \
    gl2lds16(gA1 + kb, &As[bb][2048 + woff]);                 \
    gl2lds16(gB0 + kb, &Bs[bb][woff]);                        \
    gl2lds16(gB1 + kb, &Bs[bb][2048 + woff]); }

  GSTAGE(0, 0);
  __syncthreads();

  int buf = 0;
  for (int t = 0; t < NT; ++t) {
    if (t + 1 < NT) GSTAGE(t + 1, buf ^ 1);  // issue-early; hides under MFMA
    short8 af[4], bf[4];
#pragma unroll
    for (int m = 0; m < 4; m++)
      af[m] = *reinterpret_cast<const short8*>(&As[buf][(wr + m * 16 + lo) * 32 + g * 8]);
#pragma unroll
    for (int n = 0; n < 4; n++)
      bf[n] = *reinterpret_cast<const short8*>(&Bs[buf][(wc + n * 16 + lo) * 32 + g * 8]);
    __builtin_amdgcn_s_setprio(1);
#pragma unroll
    for (int m = 0; m < 4; m++)
#pragma unroll
      for (int n = 0; n < 4; n++)
        acc[m][n] = __builtin_amdgcn_mfma_f32_16x16x32_bf16(af[m], bf[n], acc[m][n], 0, 0, 0);
    __builtin_amdgcn_s_setprio(0);
    __syncthreads();  // drains next-tile stage + orders buf reuse
    buf ^= 1;
  }
#undef GSTAGE

#pragma unroll
  for (int m = 0; m < 4; m++) {
#pragma unroll
    for (int n = 0; n < 4; n++) {
      const int col = (int)brow0 + wc + n * 16 + lo;
      const float bv = bias[col];
#pragma unroll
      for (int r = 0; r < 4; r++) {
        const int row = (int)arow0 + wr + m * 16 + g * 4 + r;
        const float v = acc[m][n][r] + bv;
        if (MODE == 0) {
          unsigned short* dst = reinterpret_cast<unsigned short*>(out);
          const int which = col >> 10, rem = col & 1023;
          const int h = rem >> 6, d = rem & 63;
          const int b = row >> 11, s = row & 2047;
          size_t idx;
          if (which == 2)  // V transposed: [bh][d][s]
            idx = ((size_t)64 + (size_t)(b * 16 + h)) * 2048 * 64 + (size_t)d * 2048 + s;
          else
            idx = ((size_t)which * 32 + (size_t)(b * 16 + h)) * 2048 * 64 + (size_t)s * 64 + d;
          dst[idx] = f2b(v);
        } else {
          reinterpret_cast<float*>(out)[(size_t)row * N + col] = v;
        }
      }
    }
  }
}

// ---------------- causal flash attention, block-cooperative LDS staging ----------------
// Q/K: [bh][2048][64]. Vt: [bh][64][2048]. Out Ab: [B][S][H*64].
__global__ __launch_bounds__(256, 4)
void attn_kernel(const unsigned short* __restrict__ Qb, const unsigned short* __restrict__ Kb,
                 const unsigned short* __restrict__ Vt, unsigned short* __restrict__ Ab) {
  constexpr int S = 2048, HD = 64;
  __shared__ __align__(16) unsigned short Ks[2][2][2048];
  __shared__ __align__(16) unsigned short Vs[2][2][2048];
  const int tid = threadIdx.x;
  const int lane = tid & 63, wave = tid >> 6;
  const int lo = lane & 15, g = lane >> 4;
  const int qblk = 31 - (blockIdx.x >> 5);  // LPT: big tiles first
  const int bh = blockIdx.x & 31;           // bh-interleave: 4 heads per XCD
  const int qbase = qblk * 64 + wave * 16;
  const unsigned short* Qh = Qb + (size_t)bh * S * HD;
  const unsigned short* Kh = Kb + (size_t)bh * S * HD;
  const unsigned short* Vh = Vt + (size_t)bh * HD * S;

  const short8 qf0 = *reinterpret_cast<const short8*>(Qh + (size_t)(qbase + lo) * HD + g * 8);
  const short8 qf1 = *reinterpret_cast<const short8*>(Qh + (size_t)(qbase + lo) * HD + 32 + g * 8);

  const int kr = tid >> 3, ku = tid & 7;
  const unsigned short* kgs = Kh + (size_t)kr * HD + ((ku ^ (kr & 7)) << 3);
  const int vd = tid >> 2, vu = tid & 3;
  const unsigned short* vgs = Vh + (size_t)vd * S + ((vu ^ (vd & 3)) << 3);
  const int woff = wave * 512;

#define STAGE(tt, bb)                                                    \
  { const int k0e = (tt) * 64;                                           \
    gl2lds16(kgs + (size_t)k0e * HD,        &Ks[bb][0][woff]);           \
    gl2lds16(kgs + (size_t)(k0e + 32) * HD, &Ks[bb][1][woff]);           \
    gl2lds16(vgs + k0e,                     &Vs[bb][0][woff]);           \
    gl2lds16(vgs + k0e + 32,                &Vs[bb][1][woff]); }

  const int kswz0 = ((g ^ (lo & 7)) << 3);
  const int kswz1 = (((g + 4) ^ (lo & 7)) << 3);
  const int vsw0 = ((((g >> 1)) ^ (lo & 3)) << 3) + (g & 1) * 4;
  const int vsw1 = ((((g >> 1) + 2) ^ (lo & 3)) << 3) + (g & 1) * 4;

  float mrun = -1e30f, lsum = 0.f;
  f32x4 o0 = {}, o1 = {}, o2 = {}, o3 = {};
  const int q_lane = qbase + lo;
  const int nt = qblk + 1;

  STAGE(0, 0);
  __syncthreads();

  int buf = 0;
  for (int t = 0; t < nt; ++t) {
    if (t + 1 < nt) STAGE(t + 1, buf ^ 1);
#pragma unroll
    for (int sc = 0; sc < 2; ++sc) {
      const unsigned short* Kt = &Ks[buf][sc][0];
      const unsigned short* Vl = &Vs[buf][sc][0];
      const int kk0 = t * 64 + sc * 32;

      const short8 kf00 = *reinterpret_cast<const short8*>(Kt + lo * 64 + kswz0);
      const short8 kf01 = *reinterpret_cast<const short8*>(Kt + lo * 64 + kswz1);
      const short8 kf10 = *reinterpret_cast<const short8*>(Kt + (16 + lo) * 64 + kswz0);
      const short8 kf11 = *reinterpret_cast<const short8*>(Kt + (16 + lo) * 64 + kswz1);

      f32x4 z0 = {0.f, 0.f, 0.f, 0.f}, z1 = {0.f, 0.f, 0.f, 0.f};
      __builtin_amdgcn_s_setprio(1);
      z0 = __builtin_amdgcn_mfma_f32_16x16x32_bf16(kf00, qf0, z0, 0, 0, 0);
      z0 = __builtin_amdgcn_mfma_f32_16x16x32_bf16(kf01, qf1, z0, 0, 0, 0);
      z1 = __builtin_amdgcn_mfma_f32_16x16x32_bf16(kf10, qf0, z1, 0, 0, 0);
      z1 = __builtin_amdgcn_mfma_f32_16x16x32_bf16(kf11, qf1, z1, 0, 0, 0);
      __builtin_amdgcn_s_setprio(0);

      float s[8];
#pragma unroll
      for (int j = 0; j < 8; j++) {
        const int kk = kk0 + ((j >> 2) << 4) + g * 4 + (j & 3);
        const float v = ((j >> 2) ? z1[j & 3] : z0[j & 3]) * 0.125f;
        s[j] = (kk > q_lane) ? -10000.f : v;
      }
      float tmax = s[0];
#pragma unroll
      for (int j = 1; j < 8; j++) tmax = fmaxf(tmax, s[j]);
      tmax = fmaxf(tmax, __shfl_xor(tmax, 16));
      tmax = fmaxf(tmax, __shfl_xor(tmax, 32));
      const float mn = fmaxf(mrun, tmax);
      const float cf = __expf(mrun - mn);
      mrun = mn;
      float ps = 0.f;
      short8 pf;
#pragma unroll
      for (int j = 0; j < 8; j++) {
        const float p = __expf(s[j] - mn);
        ps += p;
        pf[j] = (short)f2b(p);
      }
      lsum = lsum * cf + ps;
#pragma unroll
      for (int r = 0; r < 4; r++) {
        const float cr = __shfl(cf, g * 4 + r);
        o0[r] *= cr; o1[r] *= cr; o2[r] *= cr; o3[r] *= cr;
      }

      short8 vf0, vf1, vf2, vf3;
      {
        short4v a0 = *reinterpret_cast<const short4v*>(Vl + (lo +  0) * 32 + vsw0);
        short4v b0 = *reinterpret_cast<const short4v*>(Vl + (lo +  0) * 32 + vsw1);
        short4v a1 = *reinterpret_cast<const short4v*>(Vl + (lo + 16) * 32 + vsw0);
        short4v b1 = *reinterpret_cast<const short4v*>(Vl + (lo + 16) * 32 + vsw1);
        short4v a2 = *reinterpret_cast<const short4v*>(Vl + (lo + 32) * 32 + vsw0);
        short4v b2 = *reinterpret_cast<const short4v*>(Vl + (lo + 32) * 32 + vsw1);
        short4v a3 = *reinterpret_cast<const short4v*>(Vl + (lo + 48) * 32 + vsw0);
        short4v b3 = *reinterpret_cast<const short4v*>(Vl + (lo + 48) * 32 + vsw1);
        vf0 = __builtin_shufflevector(a0, b0, 0, 1, 2, 3, 4, 5, 6, 7);
        vf1 = __builtin_shufflevector(a1, b1, 0, 1, 2, 3, 4, 5, 6, 7);
        vf2 = __builtin_shufflevector(a2, b2, 0, 1, 2, 3, 4, 5, 6, 7);
        vf3 = __builtin_shufflevector(a3, b3, 0, 1, 2, 3, 4, 5, 6, 7);
      }
      __builtin_amdgcn_s_setprio(1);
      o0 = __builtin_amdgcn_mfma_f32_16x16x32_bf16(pf, vf0, o0, 0, 0, 0);
      o1 = __builtin_amdgcn_mfma_f32_16x16x32_bf16(pf, vf1, o1, 0, 0, 0);
      o2 = __builtin_amdgcn_mfma_f32_16x16x32_bf16(pf, vf2, o2, 0, 0, 0);
      o3 = __builtin_amdgcn_mfma_f32_16x16x32_bf16(pf, vf3, o3, 0, 0, 0);
      __builtin_amdgcn_s_setprio(0);
    }
    __syncthreads();
    buf ^= 1;
  }
#undef STAGE

  lsum += __shfl_xor(lsum, 16);
  lsum += __shfl_xor(lsum, 32);

  const int b = bh >> 4, h = bh & 15;
#pragma unroll
  for (int r = 0; r < 4; r++) {
    const float li = 1.f / __shfl(lsum, g * 4 + r);
    const int srow = qbase + g * 4 + r;
    unsigned short* dst = Ab + ((size_t)b * S + srow) * 1024 + h * 64 + lo;
    dst[0]  = f2b(o0[r] * li);
    dst[16] = f2b(o1[r] * li);
    dst[32] = f2b(o2[r] * li);
    dst[48] = f2b(o3[r] * li);
  }
}

extern "C" void kernel_launch(void* const* d_in, const int* in_sizes, int n_in,
                              void* d_out, int out_size, void* d_ws, size_t ws_size,
                              hipStream_t stream) {
  const float* hs       = (const float*)d_in[0];
  const float* c_attn_w = (const float*)d_in[1];
  const float* c_attn_b = (const float*)d_in[2];
  const float* c_proj_w = (const float*)d_in[3];
  const float* c_proj_b = (const float*)d_in[4];

  char* ws = (char*)d_ws;
  unsigned short* Xb    = (unsigned short*)ws;  ws += (size_t)4096 * 1024 * 2;
  unsigned short* Wqkvt = (unsigned short*)ws;  ws += (size_t)3072 * 1024 * 2;
  unsigned short* Wpt   = (unsigned short*)ws;  ws += (size_t)1024 * 1024 * 2;
  unsigned short* QKV   = (unsigned short*)ws;  ws += (size_t)3 * 32 * 2048 * 64 * 2;
  unsigned short* Ab    = (unsigned short*)ws;  ws += (size_t)4096 * 1024 * 2;

  unsigned short* Qb = QKV;
  unsigned short* Kb = QKV + (size_t)32 * 2048 * 64;
  unsigned short* Vt = QKV + (size_t)2 * 32 * 2048 * 64;  // [bh][64][2048], written by gemm<0>

  prep_kernel<<<8192, 256, 0, stream>>>(hs, Xb, c_attn_w, Wqkvt, c_proj_w, Wpt);
  gemm_bt<0><<<32 * 24, 256, 0, stream>>>(Xb, Wqkvt, c_attn_b, QKV, 3072);
  attn_kernel<<<32 * 32, 256, 0, stream>>>(Qb, Kb, Vt, Ab);
  gemm_bt<1><<<32 * 8, 256, 0, stream>>>(Ab, Wpt, c_proj_b, d_out, 1024);
}